// Round 1
// baseline (114.133 us; speedup 1.0000x reference)
//
#include <hip/hip_runtime.h>

#define MAX_SEQ_LEN 512
#define NUM_HEADS 12
#define TABLE_SIZE 1025   // 2*MAX_SEQ_LEN + 1
#define BATCH 4
#define SEQ 512

// ---------------------------------------------------------------------------
// Kernel 1: fold the 4H->H linear layer into the tables.
// proj[t][idx][h] = sum_f pe_t[idx][f] * W[t*12+f][h]  (+ b[h] folded into t=0)
// Output: 4 * 1025 * 12 floats in d_ws (196,800 B).
// ---------------------------------------------------------------------------
__global__ void proj_tables_kernel(const float* __restrict__ pe_ss,
                                   const float* __restrict__ pe_se,
                                   const float* __restrict__ pe_es,
                                   const float* __restrict__ pe_ee,
                                   const float* __restrict__ W,
                                   const float* __restrict__ bias,
                                   float* __restrict__ proj) {
    int tid = blockIdx.x * blockDim.x + threadIdx.x;   // one thread per (t, idx)
    if (tid >= 4 * TABLE_SIZE) return;
    int t   = tid / TABLE_SIZE;
    int idx = tid - t * TABLE_SIZE;

    const float* pe = (t == 0 ? pe_ss : t == 1 ? pe_se : t == 2 ? pe_es : pe_ee)
                      + idx * NUM_HEADS;
    float pev[NUM_HEADS];
#pragma unroll
    for (int f = 0; f < NUM_HEADS; ++f) pev[f] = pe[f];

    float* out = proj + (size_t)tid * NUM_HEADS;
#pragma unroll
    for (int h = 0; h < NUM_HEADS; ++h) {
        float acc = (t == 0) ? bias[h] : 0.0f;
#pragma unroll
        for (int f = 0; f < NUM_HEADS; ++f)
            acc += pev[f] * W[(t * NUM_HEADS + f) * NUM_HEADS + h];
        out[h] = acc;
    }
}

// ---------------------------------------------------------------------------
// Kernel 2: main fusion. One block per (b, i) row; 128 threads; each thread
// owns 4 consecutive j. Per output element: 4 gathered row-adds + ReLU.
// Writes out[b][h][i][j] as float4 per head (coalesced 1 KiB/wave/store).
// ---------------------------------------------------------------------------
__global__ __launch_bounds__(128)
void fuse_kernel(const int* __restrict__ pos_s,
                 const int* __restrict__ pos_e,
                 const float* __restrict__ proj,
                 float* __restrict__ out) {
    const int bi = blockIdx.x;
    const int b  = bi >> 9;          // / SEQ
    const int i  = bi & (SEQ - 1);   // % SEQ

    // wave-uniform row positions (compiler scalarizes these)
    const int ps_i = pos_s[b * SEQ + i];
    const int pe_i = pos_e[b * SEQ + i];

    const int j0 = threadIdx.x * 4;
    const int4 js4 = *reinterpret_cast<const int4*>(pos_s + b * SEQ + j0);
    const int4 je4 = *reinterpret_cast<const int4*>(pos_e + b * SEQ + j0);
    const int jsa[4] = {js4.x, js4.y, js4.z, js4.w};
    const int jea[4] = {je4.x, je4.y, je4.z, je4.w};

    const float* __restrict__ pss = proj;
    const float* __restrict__ pse = proj + 1 * TABLE_SIZE * NUM_HEADS;
    const float* __restrict__ pes = proj + 2 * TABLE_SIZE * NUM_HEADS;
    const float* __restrict__ pee = proj + 3 * TABLE_SIZE * NUM_HEADS;

    float acc[4][NUM_HEADS];

#pragma unroll
    for (int k = 0; k < 4; ++k) {
        const int iss = ps_i - jsa[k] + MAX_SEQ_LEN;
        const int ise = ps_i - jea[k] + MAX_SEQ_LEN;
        const int ies = pe_i - jsa[k] + MAX_SEQ_LEN;
        const int iee = pe_i - jea[k] + MAX_SEQ_LEN;

        const float4* r0 = reinterpret_cast<const float4*>(pss + iss * NUM_HEADS);
        const float4* r1 = reinterpret_cast<const float4*>(pse + ise * NUM_HEADS);
        const float4* r2 = reinterpret_cast<const float4*>(pes + ies * NUM_HEADS);
        const float4* r3 = reinterpret_cast<const float4*>(pee + iee * NUM_HEADS);

        float4 a0 = r0[0], a1 = r0[1], a2 = r0[2];
        float4 b0 = r1[0], b1 = r1[1], b2 = r1[2];
        float4 c0 = r2[0], c1 = r2[1], c2 = r2[2];
        float4 d0 = r3[0], d1 = r3[1], d2 = r3[2];

        acc[k][0]  = a0.x + b0.x + c0.x + d0.x;
        acc[k][1]  = a0.y + b0.y + c0.y + d0.y;
        acc[k][2]  = a0.z + b0.z + c0.z + d0.z;
        acc[k][3]  = a0.w + b0.w + c0.w + d0.w;
        acc[k][4]  = a1.x + b1.x + c1.x + d1.x;
        acc[k][5]  = a1.y + b1.y + c1.y + d1.y;
        acc[k][6]  = a1.z + b1.z + c1.z + d1.z;
        acc[k][7]  = a1.w + b1.w + c1.w + d1.w;
        acc[k][8]  = a2.x + b2.x + c2.x + d2.x;
        acc[k][9]  = a2.y + b2.y + c2.y + d2.y;
        acc[k][10] = a2.z + b2.z + c2.z + d2.z;
        acc[k][11] = a2.w + b2.w + c2.w + d2.w;
    }

    // ReLU + store: out[((b*12 + h)*512 + i)*512 + j0 .. +3]
    float* obase = out + (((size_t)b * NUM_HEADS) * SEQ + i) * SEQ + j0;
#pragma unroll
    for (int h = 0; h < NUM_HEADS; ++h) {
        float4 v;
        v.x = fmaxf(acc[0][h], 0.0f);
        v.y = fmaxf(acc[1][h], 0.0f);
        v.z = fmaxf(acc[2][h], 0.0f);
        v.w = fmaxf(acc[3][h], 0.0f);
        *reinterpret_cast<float4*>(obase + (size_t)h * SEQ * SEQ) = v;
    }
}

extern "C" void kernel_launch(void* const* d_in, const int* in_sizes, int n_in,
                              void* d_out, int out_size, void* d_ws, size_t ws_size,
                              hipStream_t stream) {
    const int*   pos_s = (const int*)d_in[0];
    const int*   pos_e = (const int*)d_in[1];
    const float* pe_ss = (const float*)d_in[2];
    const float* pe_se = (const float*)d_in[3];
    const float* pe_es = (const float*)d_in[4];
    const float* pe_ee = (const float*)d_in[5];
    const float* W     = (const float*)d_in[6];
    const float* bias  = (const float*)d_in[7];
    float* out  = (float*)d_out;
    float* proj = (float*)d_ws;   // 4*1025*12 floats = 196,800 B

    // Kernel 1: 4100 (t, idx) rows
    {
        int total = 4 * TABLE_SIZE;
        int block = 256;
        int grid  = (total + block - 1) / block;
        proj_tables_kernel<<<grid, block, 0, stream>>>(pe_ss, pe_se, pe_es, pe_ee,
                                                       W, bias, proj);
    }

    // Kernel 2: one block per (b, i)
    {
        dim3 grid(BATCH * SEQ);
        dim3 block(128);
        fuse_kernel<<<grid, block, 0, stream>>>(pos_s, pos_e, proj, out);
    }
}

// Round 5
// 97.151 us; speedup vs baseline: 1.1748x; 1.1748x over previous
//
#include <hip/hip_runtime.h>

#define MAX_SEQ_LEN 512
#define NUM_HEADS 12
#define TABLE_SIZE 1025   // 2*MAX_SEQ_LEN + 1
#define BATCH 4
#define SEQ 512
#define ROWF 12           // floats per table row
#define WIN 512           // rows per staged window
#define F4_PER_WIN (WIN * ROWF / 4)   // 1536 float4 per window

// ---------------------------------------------------------------------------
// Kernel 1: fold the 4H->H linear layer into the tables.
// proj[t][idx][h] = sum_f pe_t[idx][f] * W[t*12+f][h]  (+ b[h] folded into t=0)
// ---------------------------------------------------------------------------
__global__ void proj_tables_kernel(const float* __restrict__ pe_ss,
                                   const float* __restrict__ pe_se,
                                   const float* __restrict__ pe_es,
                                   const float* __restrict__ pe_ee,
                                   const float* __restrict__ W,
                                   const float* __restrict__ bias,
                                   float* __restrict__ proj) {
    int tid = blockIdx.x * blockDim.x + threadIdx.x;   // one thread per (t, idx)
    if (tid >= 4 * TABLE_SIZE) return;
    int t   = tid / TABLE_SIZE;
    int idx = tid - t * TABLE_SIZE;

    const float* pe = (t == 0 ? pe_ss : t == 1 ? pe_se : t == 2 ? pe_es : pe_ee)
                      + idx * NUM_HEADS;
    float pev[NUM_HEADS];
#pragma unroll
    for (int f = 0; f < NUM_HEADS; ++f) pev[f] = pe[f];

    float* outp = proj + (size_t)tid * NUM_HEADS;
#pragma unroll
    for (int h = 0; h < NUM_HEADS; ++h) {
        float acc = (t == 0) ? bias[h] : 0.0f;
#pragma unroll
        for (int f = 0; f < NUM_HEADS; ++f)
            acc += pev[f] * W[(t * NUM_HEADS + f) * NUM_HEADS + h];
        outp[h] = acc;
    }
}

// ---------------------------------------------------------------------------
// Kernel 2: per (b,i) block.
//   Stage composites into LDS (coalesced float4 stream loads from L2):
//     A[u-1] = proj_ss[ps_i + u] + proj_es[pe_i + u]   u in [1,512]
//     B[v-1] = proj_se[ps_i + v] + proj_ee[pe_i + v]   v in [1,512]
//   Then out[b][h][i][j] = relu( A[511-pos_s[j]][h] + B[511-pos_e[j]][h] ).
//   (idx_ss = ps-pos_s[j]+512, idx_es = pe-pos_s[j]+512: same offset, two
//    bases -> one composite row. Ditto se/ee with pos_e[j].)
// ---------------------------------------------------------------------------
__global__ __launch_bounds__(256)
void fuse_kernel(const int* __restrict__ pos_s,
                 const int* __restrict__ pos_e,
                 const float* __restrict__ proj,
                 float* __restrict__ out) {
    __shared__ float4 ldsA[F4_PER_WIN];   // 24 KiB
    __shared__ float4 ldsB[F4_PER_WIN];   // 24 KiB

    const int bi = blockIdx.x;
    const int b  = bi >> 9;          // / SEQ
    const int i  = bi & (SEQ - 1);   // % SEQ

    const int ps = pos_s[b * SEQ + i];   // wave-uniform
    const int pe = pos_e[b * SEQ + i];

    // my two j values (preload before barrier)
    const int j0 = threadIdx.x * 2;
    const int2 js = *reinterpret_cast<const int2*>(pos_s + b * SEQ + j0);
    const int2 je = *reinterpret_cast<const int2*>(pos_e + b * SEQ + j0);

    // window base pointers: (row)*48 B is 16 B aligned for any row
    const float4* __restrict__ wss = reinterpret_cast<const float4*>(
        proj + ((size_t)0 * TABLE_SIZE + ps + 1) * ROWF);
    const float4* __restrict__ wse = reinterpret_cast<const float4*>(
        proj + ((size_t)1 * TABLE_SIZE + ps + 1) * ROWF);
    const float4* __restrict__ wes = reinterpret_cast<const float4*>(
        proj + ((size_t)2 * TABLE_SIZE + pe + 1) * ROWF);
    const float4* __restrict__ wee = reinterpret_cast<const float4*>(
        proj + ((size_t)3 * TABLE_SIZE + pe + 1) * ROWF);

#pragma unroll
    for (int m = threadIdx.x; m < F4_PER_WIN; m += 256) {
        float4 x = wss[m], y = wes[m];
        ldsA[m] = make_float4(x.x + y.x, x.y + y.y, x.z + y.z, x.w + y.w);
        float4 u = wse[m], v = wee[m];
        ldsB[m] = make_float4(u.x + v.x, u.y + v.y, u.z + v.z, u.w + v.w);
    }
    __syncthreads();

    float r[2][NUM_HEADS];
#pragma unroll
    for (int k = 0; k < 2; ++k) {
        const int rA = (WIN - 1) - (k ? js.y : js.x);   // 511 - pos_s[j]
        const int rB = (WIN - 1) - (k ? je.y : je.x);   // 511 - pos_e[j]
        const float4* a  = ldsA + rA * 3;
        const float4* bb = ldsB + rB * 3;
        float4 a0 = a[0], a1 = a[1], a2 = a[2];
        float4 b0 = bb[0], b1 = bb[1], b2 = bb[2];
        r[k][0]  = fmaxf(a0.x + b0.x, 0.0f);
        r[k][1]  = fmaxf(a0.y + b0.y, 0.0f);
        r[k][2]  = fmaxf(a0.z + b0.z, 0.0f);
        r[k][3]  = fmaxf(a0.w + b0.w, 0.0f);
        r[k][4]  = fmaxf(a1.x + b1.x, 0.0f);
        r[k][5]  = fmaxf(a1.y + b1.y, 0.0f);
        r[k][6]  = fmaxf(a1.z + b1.z, 0.0f);
        r[k][7]  = fmaxf(a1.w + b1.w, 0.0f);
        r[k][8]  = fmaxf(a2.x + b2.x, 0.0f);
        r[k][9]  = fmaxf(a2.y + b2.y, 0.0f);
        r[k][10] = fmaxf(a2.z + b2.z, 0.0f);
        r[k][11] = fmaxf(a2.w + b2.w, 0.0f);
    }

    // out[((b*12 + h)*512 + i)*512 + j0], float2 per head (8 B aligned)
    float* obase = out + (((size_t)b * NUM_HEADS) * SEQ + i) * SEQ + j0;
#pragma unroll
    for (int h = 0; h < NUM_HEADS; ++h) {
        *reinterpret_cast<float2*>(obase + (size_t)h * SEQ * SEQ) =
            make_float2(r[0][h], r[1][h]);
    }
}

extern "C" void kernel_launch(void* const* d_in, const int* in_sizes, int n_in,
                              void* d_out, int out_size, void* d_ws, size_t ws_size,
                              hipStream_t stream) {
    const int*   pos_s = (const int*)d_in[0];
    const int*   pos_e = (const int*)d_in[1];
    const float* pe_ss = (const float*)d_in[2];
    const float* pe_se = (const float*)d_in[3];
    const float* pe_es = (const float*)d_in[4];
    const float* pe_ee = (const float*)d_in[5];
    const float* W     = (const float*)d_in[6];
    const float* bias  = (const float*)d_in[7];
    float* out  = (float*)d_out;
    float* proj = (float*)d_ws;   // 4*1025*12 floats = 196,800 B

    {
        int total = 4 * TABLE_SIZE;
        int block = 256;
        int grid  = (total + block - 1) / block;
        proj_tables_kernel<<<grid, block, 0, stream>>>(pe_ss, pe_se, pe_es, pe_ee,
                                                       W, bias, proj);
    }
    {
        dim3 grid(BATCH * SEQ);
        dim3 block(256);
        fuse_kernel<<<grid, block, 0, stream>>>(pos_s, pos_e, proj, out);
    }
}